// Round 6
// baseline (522.297 us; speedup 1.0000x reference)
//
#include <hip/hip_runtime.h>

// EncoderBlock: x:[2,2048,1024] FP32 in/out. Internal fp16 MFMA.
// B=2 S=2048 D=1024 H=16 DH=64 FF=4096, T=4096 tokens.
// ws (32MB): R0 8MB: h -> Vt -> woT -> h(LN2)
//            R1..R3 24MB: fused QKV [4096][3072] -> (attn-out in Q slice) -> f(R1+R2) + wscratch(R3)
// d_out (16MB): wqkvT fp16 scratch (6MB) -> x1 fp32 -> final output.

typedef _Float16 half8 __attribute__((ext_vector_type(8)));
typedef _Float16 half4 __attribute__((ext_vector_type(4)));
typedef float floatx4 __attribute__((ext_vector_type(4)));

__device__ __forceinline__ void async16(const void* g, void* l) {
    __builtin_amdgcn_global_load_lds((const __attribute__((address_space(1))) unsigned int*)g,
                                     (__attribute__((address_space(3))) unsigned int*)l,
                                     16, 0, 0);
}

// ---------------- LayerNorm fp32 -> fp16 (ddof=1, g*(x-mean)/(std+eps)+b) ----
__global__ __launch_bounds__(256) void ln_kernel(const float* __restrict__ x,
                                                 const float* __restrict__ g,
                                                 const float* __restrict__ be,
                                                 _Float16* __restrict__ out) {
    int row = blockIdx.x;
    int tid = threadIdx.x;
    floatx4 v = ((const floatx4*)(x + (size_t)row * 1024))[tid];
    float s = 0.f, ss = 0.f;
#pragma unroll
    for (int i = 0; i < 4; i++) { s += v[i]; ss += v[i] * v[i]; }
#pragma unroll
    for (int off = 1; off < 64; off <<= 1) {
        s += __shfl_xor(s, off);
        ss += __shfl_xor(ss, off);
    }
    __shared__ float sm[8];
    int wave = tid >> 6, lane = tid & 63;
    if (lane == 0) { sm[wave] = s; sm[wave + 4] = ss; }
    __syncthreads();
    s = sm[0] + sm[1] + sm[2] + sm[3];
    ss = sm[4] + sm[5] + sm[6] + sm[7];
    float mean = s * (1.f / 1024.f);
    float var = (ss - s * mean) * (1.f / 1023.f);
    float rs = 1.f / (sqrtf(fmaxf(var, 0.f)) + 1e-6f);
    floatx4 gv = ((const floatx4*)g)[tid];
    floatx4 bv = ((const floatx4*)be)[tid];
    half4 o;
#pragma unroll
    for (int i = 0; i < 4; i++) o[i] = (_Float16)(gv[i] * (v[i] - mean) * rs + bv[i]);
    ((half4*)(out + (size_t)row * 1024))[tid] = o;
}

// ------- Transpose-convert: W[Kr][Nr] fp32 (row stride ldW) -> WT[Nr][Kr] fp16 -----
__global__ __launch_bounds__(256) void convt_kernel(const float* __restrict__ W, int ldW,
                                                    _Float16* __restrict__ WT, int Kr) {
    __shared__ float t[64][65];
    int n0 = blockIdx.x * 64, k0 = blockIdx.y * 64;
    int tid = threadIdx.x;
    int r = tid >> 4, c4 = (tid & 15) * 4;
#pragma unroll
    for (int p = 0; p < 4; p++) {
        floatx4 v = *(const floatx4*)(W + (size_t)(k0 + r + p * 16) * ldW + n0 + c4);
#pragma unroll
        for (int j = 0; j < 4; j++) t[c4 + j][r + p * 16] = v[j];
    }
    __syncthreads();
#pragma unroll
    for (int p = 0; p < 4; p++) {
        int rr = r + p * 16;
        half4 o;
#pragma unroll
        for (int j = 0; j < 4; j++) o[j] = (_Float16)t[rr][c4 + j];
        *(half4*)(WT + (size_t)(n0 + rr) * Kr + k0 + c4) = o;
    }
}

// ------- V transpose fp16: V[4096][ldv] (64-col head slices) -> Vt[bh=32][dh=64][s=2048] --
__global__ __launch_bounds__(256) void transv_kernel(const _Float16* __restrict__ V, int ldv,
                                                     _Float16* __restrict__ Vt) {
    __shared__ _Float16 t[64][72];
    int t0 = blockIdx.x * 64, d0 = blockIdx.y * 64;
    int tid = threadIdx.x;
#pragma unroll
    for (int i = 0; i < 2; i++) {
        int v = tid + i * 256;
        int r = v >> 3, c = (v & 7) * 8;
        half8 vv = *(const half8*)(V + (size_t)(t0 + r) * ldv + d0 + c);
#pragma unroll
        for (int j = 0; j < 8; j++) t[c + j][r] = vv[j];
    }
    __syncthreads();
    int bh = (t0 >> 11) * 16 + (d0 >> 6);
    int sbase = t0 & 2047;
#pragma unroll
    for (int i = 0; i < 2; i++) {
        int v = tid + i * 256;
        int r = v >> 3, c = (v & 7) * 8;
        half8 o = *(const half8*)&t[r][c];
        *(half8*)(Vt + ((size_t)bh * 64 + r) * 2048 + sbase + c) = o;
    }
}

// ------- MFMA GEMM 128x128 (m97-style): C = [relu](A@BT^T + bias) + res --------
// A [M][lda] fp16, BT [N][K] fp16. 4 waves x (64x64), BK=64.
// async16+XOR-swizzle staging; 32 MFMA : 16 ds_read_b128 per K-iter.
__global__ __launch_bounds__(256) void gemm_t(const _Float16* __restrict__ A, int lda,
                                              const _Float16* __restrict__ BT,
                                              const float* __restrict__ bias,
                                              const float* res, void* Cout,
                                              int N, int K, int relu_flag, int out_fp16) {
    __shared__ _Float16 As[128 * 64];   // 16KB
    __shared__ _Float16 Bs[128 * 64];   // 16KB
    int tid = threadIdx.x;
    int wave = tid >> 6, lane = tid & 63, quad = lane >> 4, l15 = lane & 15;
    int bm = blockIdx.y * 128, bn = blockIdx.x * 128;
    int wm = (wave >> 1) * 64, wn = (wave & 1) * 64;
    int lrow = lane >> 3, lch = lane & 7;

    floatx4 acc[4][4];
#pragma unroll
    for (int im = 0; im < 4; im++)
#pragma unroll
        for (int in = 0; in < 4; in++)
#pragma unroll
            for (int r = 0; r < 4; r++) acc[im][in][r] = 0.f;

    for (int k0 = 0; k0 < K; k0 += 64) {
        __syncthreads();
        // 16 row-groups of 8 each; wave stages groups 4w..4w+3
#pragma unroll
        for (int ia = 0; ia < 4; ia++) {
            int g = 4 * wave + ia;
            int row = g * 8 + lrow;
            int ch = lch ^ (row & 7);
            async16(A + (size_t)(bm + row) * lda + k0 + ch * 8, &As[g * 512]);
        }
#pragma unroll
        for (int ib = 0; ib < 4; ib++) {
            int g = 4 * wave + ib;
            int row = g * 8 + lrow;
            int ch = lch ^ (row & 7);
            async16(BT + (size_t)(bn + row) * K + k0 + ch * 8, &Bs[g * 512]);
        }
        __syncthreads();

        half8 af[4][2], bf[4][2];
#pragma unroll
        for (int kk = 0; kk < 2; kk++) {
#pragma unroll
            for (int im = 0; im < 4; im++) {
                int m = wm + im * 16 + l15;
                af[im][kk] = *(const half8*)&As[m * 64 + ((((kk << 2) | quad) ^ (m & 7)) << 3)];
            }
#pragma unroll
            for (int in = 0; in < 4; in++) {
                int n = wn + in * 16 + l15;
                bf[in][kk] = *(const half8*)&Bs[n * 64 + ((((kk << 2) | quad) ^ (n & 7)) << 3)];
            }
        }
#pragma unroll
        for (int kk = 0; kk < 2; kk++)
#pragma unroll
            for (int im = 0; im < 4; im++)
#pragma unroll
                for (int in = 0; in < 4; in++)
                    acc[im][in] = __builtin_amdgcn_mfma_f32_16x16x32_f16(af[im][kk], bf[in][kk],
                                                                         acc[im][in], 0, 0, 0);
    }
#pragma unroll
    for (int im = 0; im < 4; im++)
#pragma unroll
        for (int in = 0; in < 4; in++)
#pragma unroll
            for (int r = 0; r < 4; r++) {
                int row = bm + wm + im * 16 + quad * 4 + r;
                int col = bn + wn + in * 16 + l15;
                float val = acc[im][in][r];
                if (bias) val += bias[col];
                if (relu_flag) val = fmaxf(val, 0.f);
                if (res) val += res[(size_t)row * N + col];
                if (out_fp16) ((_Float16*)Cout)[(size_t)row * N + col] = (_Float16)val;
                else          ((float*)Cout)[(size_t)row * N + col] = val;
            }
}

// ---------------- Flash attention v2 (round-5 structure, + stride param) --------
__global__ __launch_bounds__(256) void attn_kernel(const _Float16* Q,
                                                   const _Float16* __restrict__ K,
                                                   const _Float16* __restrict__ Vt,
                                                   _Float16* O, int ld) {
    __shared__ _Float16 Qs[64 * 64];
    __shared__ _Float16 Ks[64 * 64];
    __shared__ _Float16 Vs[64 * 64];
    int qt = blockIdx.x, bh = blockIdx.y;
    int b = bh >> 4, h = bh & 15;
    int col0 = h * 64, tbase = b * 2048;
    int tid = threadIdx.x;
    int wave = tid >> 6, lane = tid & 63, quad = lane >> 4, l15 = lane & 15;
    int lrow = lane >> 3, lch = lane & 7;

#pragma unroll
    for (int i = 0; i < 2; i++) {
        int g = 2 * wave + i;
        int row = g * 8 + lrow;
        int ch = lch ^ (row & 7);
        async16(Q + (size_t)(tbase + qt * 64 + row) * ld + col0 + ch * 8, &Qs[g * 512]);
    }

    floatx4 o_acc[4];
#pragma unroll
    for (int im = 0; im < 4; im++)
#pragma unroll
        for (int r = 0; r < 4; r++) o_acc[im][r] = 0.f;
    float m_i = -1e30f, l_i = 0.f;

    for (int kt = 0; kt < 32; kt++) {
        __syncthreads();
#pragma unroll
        for (int i = 0; i < 2; i++) {
            int g = 2 * wave + i;
            int row = g * 8 + lrow;
            int ch = lch ^ (row & 7);
            async16(K + (size_t)(tbase + kt * 64 + row) * ld + col0 + ch * 8, &Ks[g * 512]);
            async16(Vt + ((size_t)bh * 64 + row) * 2048 + kt * 64 + ch * 8, &Vs[g * 512]);
        }
        __syncthreads();

        int rowq = 16 * wave + l15;
        half8 bq[2];
#pragma unroll
        for (int kk = 0; kk < 2; kk++)
            bq[kk] = *(const half8*)&Qs[rowq * 64 + ((((kk << 2) | quad) ^ (rowq & 7)) << 3)];
        floatx4 s_acc[4];
#pragma unroll
        for (int jn = 0; jn < 4; jn++)
#pragma unroll
            for (int r = 0; r < 4; r++) s_acc[jn][r] = 0.f;
#pragma unroll
        for (int jn = 0; jn < 4; jn++) {
            int rowk = 16 * jn + l15;
#pragma unroll
            for (int kk = 0; kk < 2; kk++) {
                half8 ak = *(const half8*)&Ks[rowk * 64 + ((((kk << 2) | quad) ^ (rowk & 7)) << 3)];
                s_acc[jn] = __builtin_amdgcn_mfma_f32_16x16x32_f16(ak, bq[kk], s_acc[jn], 0, 0, 0);
            }
        }

        float mx = -1e30f;
#pragma unroll
        for (int jn = 0; jn < 4; jn++)
#pragma unroll
            for (int r = 0; r < 4; r++) {
                s_acc[jn][r] *= 0.125f;
                mx = fmaxf(mx, s_acc[jn][r]);
            }
        mx = fmaxf(mx, __shfl_xor(mx, 16));
        mx = fmaxf(mx, __shfl_xor(mx, 32));
        float mnew = fmaxf(m_i, mx);
        float dd = m_i - mnew;
        float alpha = (dd < -60.f) ? 0.f : __expf(dd);
        m_i = mnew;

        float sum = 0.f;
#pragma unroll
        for (int jn = 0; jn < 4; jn++)
#pragma unroll
            for (int r = 0; r < 4; r++) {
                float d2 = s_acc[jn][r] - mnew;
                float p = (d2 < -60.f) ? 0.f : __expf(d2);
                s_acc[jn][r] = p;
                sum += p;
            }
        sum += __shfl_xor(sum, 16);
        sum += __shfl_xor(sum, 32);
        l_i = l_i * alpha + sum;

        half4 pb[4];
#pragma unroll
        for (int jn = 0; jn < 4; jn++)
#pragma unroll
            for (int r = 0; r < 4; r++) pb[jn][r] = (_Float16)s_acc[jn][r];

#pragma unroll
        for (int im = 0; im < 4; im++)
#pragma unroll
            for (int r = 0; r < 4; r++) o_acc[im][r] *= alpha;
#pragma unroll
        for (int im = 0; im < 4; im++) {
            int rowv = 16 * im + l15;
#pragma unroll
            for (int ks = 0; ks < 4; ks++) {
                int off = rowv * 128 + ((((2 * ks) | (quad >> 1)) ^ (rowv & 7)) << 4) + (quad & 1) * 8;
                half4 av = *(const half4*)((const char*)Vs + off);
                o_acc[im] = __builtin_amdgcn_mfma_f32_16x16x16f16(av, pb[ks], o_acc[im], 0, 0, 0);
            }
        }
    }

    float rl = 1.f / l_i;
#pragma unroll
    for (int im = 0; im < 4; im++) {
        half4 o;
#pragma unroll
        for (int r = 0; r < 4; r++) o[r] = (_Float16)(o_acc[im][r] * rl);
        *(half4*)&O[(size_t)(tbase + qt * 64 + wave * 16 + l15) * ld + col0 + im * 16 + quad * 4] = o;
    }
}

extern "C" void kernel_launch(void* const* d_in, const int* in_sizes, int n_in,
                              void* d_out, int out_size, void* d_ws, size_t ws_size,
                              hipStream_t stream) {
    const float* x   = (const float*)d_in[0];
    const float* wq  = (const float*)d_in[1];
    const float* wk  = (const float*)d_in[2];
    const float* wv  = (const float*)d_in[3];
    const float* wo  = (const float*)d_in[4];
    const float* w1  = (const float*)d_in[5];
    const float* b1  = (const float*)d_in[6];
    const float* w2  = (const float*)d_in[7];
    const float* b2  = (const float*)d_in[8];
    const float* g1  = (const float*)d_in[9];
    const float* be1 = (const float*)d_in[10];
    const float* g2  = (const float*)d_in[11];
    const float* be2 = (const float*)d_in[12];

    const size_t M1 = (size_t)1 << 20;
    _Float16* R0  = (_Float16*)d_ws;       // h -> Vt -> woT -> h(LN2)
    _Float16* QKV = R0 + 4 * M1;           // [4096][3072] fused; later f(R1+R2) + scratch(R3)
    _Float16* R3  = R0 + 12 * M1;

    _Float16* wqkvT = (_Float16*)d_out;    // [3072][1024] fp16 scratch (6MB, dead after QKV GEMM)
    float* x1 = (float*)d_out;
    float* out = (float*)d_out;

    dim3 blk(256);

    // fused QKV weight transpose-convert
    convt_kernel<<<dim3(16, 16), blk, 0, stream>>>(wq, 1024, wqkvT, 1024);
    convt_kernel<<<dim3(16, 16), blk, 0, stream>>>(wk, 1024, wqkvT + (size_t)1024 * 1024, 1024);
    convt_kernel<<<dim3(16, 16), blk, 0, stream>>>(wv, 1024, wqkvT + (size_t)2048 * 1024, 1024);
    // h = LN1(x)
    ln_kernel<<<4096, blk, 0, stream>>>(x, g1, be1, R0);
    // fused QKV GEMM: [4096,3072] = h @ wqkvT^T
    gemm_t<<<dim3(24, 32), blk, 0, stream>>>(R0, 1024, wqkvT, nullptr, nullptr, QKV, 3072, 1024, 0, 1);
    // Vt (h dead) from V slice (cols 2048..3071)
    transv_kernel<<<dim3(64, 16), blk, 0, stream>>>(QKV + 2048, 3072, R0);
    // attention in-place over Q slice
    attn_kernel<<<dim3(32, 32), blk, 0, stream>>>(QKV, QKV + 1024, R0, QKV, 3072);
    // woT -> R0 (Vt dead), then x1 = attnout @ wo + x -> d_out
    convt_kernel<<<dim3(16, 16), blk, 0, stream>>>(wo, 1024, R0, 1024);
    gemm_t<<<dim3(8, 32), blk, 0, stream>>>(QKV, 3072, R0, nullptr, x, x1, 1024, 1024, 0, 0);
    // h = LN2(x1) -> R0 (woT dead)
    ln_kernel<<<4096, blk, 0, stream>>>(x1, g2, be2, R0);
    // FFN in two 2048-wide halves; f = [4096,2048] fp16 over R1+R2 (QKV dead)
    _Float16* f = QKV;
    for (int hh = 0; hh < 2; hh++) {
        _Float16* w1Th = R3;
        _Float16* w2Th = R3 + 2 * M1;
        convt_kernel<<<dim3(32, 16), blk, 0, stream>>>(w1 + hh * 2048, 4096, w1Th, 1024);
        gemm_t<<<dim3(16, 32), blk, 0, stream>>>(R0, 1024, w1Th, b1 + hh * 2048, nullptr, f,
                                                 2048, 1024, 1, 1);
        convt_kernel<<<dim3(16, 32), blk, 0, stream>>>(w2 + (size_t)hh * 2048 * 1024, 1024, w2Th, 2048);
        gemm_t<<<dim3(8, 32), blk, 0, stream>>>(f, 2048, w2Th, (hh == 1) ? b2 : nullptr, x1, out,
                                                1024, 2048, 0, 0);
    }
}

// Round 7
// 441.208 us; speedup vs baseline: 1.1838x; 1.1838x over previous
//
#include <hip/hip_runtime.h>

// EncoderBlock: x:[2,2048,1024] FP32 in/out. Internal fp16 MFMA.
// B=2 S=2048 D=1024 H=16 DH=64 FF=4096, T=4096 tokens.
// ws (32MB): R0 8MB: h -> Vt -> woT -> h(LN2)
//            R1..R3 24MB: fused QKV [4096][3072] -> (attn-out in Q slice) -> f(R1+R2) + wscratch(R3)
// d_out (16MB): wqkvT fp16 scratch (6MB) -> x1 fp32 -> final output.
// GEMM: 64x128 tile (round-5 proven config; 128x128 regressed in round 6).

typedef _Float16 half8 __attribute__((ext_vector_type(8)));
typedef _Float16 half4 __attribute__((ext_vector_type(4)));
typedef float floatx4 __attribute__((ext_vector_type(4)));

__device__ __forceinline__ void async16(const void* g, void* l) {
    __builtin_amdgcn_global_load_lds((const __attribute__((address_space(1))) unsigned int*)g,
                                     (__attribute__((address_space(3))) unsigned int*)l,
                                     16, 0, 0);
}

// ---------------- LayerNorm fp32 -> fp16 (ddof=1, g*(x-mean)/(std+eps)+b) ----
__global__ __launch_bounds__(256) void ln_kernel(const float* __restrict__ x,
                                                 const float* __restrict__ g,
                                                 const float* __restrict__ be,
                                                 _Float16* __restrict__ out) {
    int row = blockIdx.x;
    int tid = threadIdx.x;
    floatx4 v = ((const floatx4*)(x + (size_t)row * 1024))[tid];
    float s = 0.f, ss = 0.f;
#pragma unroll
    for (int i = 0; i < 4; i++) { s += v[i]; ss += v[i] * v[i]; }
#pragma unroll
    for (int off = 1; off < 64; off <<= 1) {
        s += __shfl_xor(s, off);
        ss += __shfl_xor(ss, off);
    }
    __shared__ float sm[8];
    int wave = tid >> 6, lane = tid & 63;
    if (lane == 0) { sm[wave] = s; sm[wave + 4] = ss; }
    __syncthreads();
    s = sm[0] + sm[1] + sm[2] + sm[3];
    ss = sm[4] + sm[5] + sm[6] + sm[7];
    float mean = s * (1.f / 1024.f);
    float var = (ss - s * mean) * (1.f / 1023.f);
    float rs = 1.f / (sqrtf(fmaxf(var, 0.f)) + 1e-6f);
    floatx4 gv = ((const floatx4*)g)[tid];
    floatx4 bv = ((const floatx4*)be)[tid];
    half4 o;
#pragma unroll
    for (int i = 0; i < 4; i++) o[i] = (_Float16)(gv[i] * (v[i] - mean) * rs + bv[i]);
    ((half4*)(out + (size_t)row * 1024))[tid] = o;
}

// ------- Transpose-convert: W[Kr][Nr] fp32 (row stride ldW) -> WT[Nr][Kr] fp16 * scale --
__global__ __launch_bounds__(256) void convt_kernel(const float* __restrict__ W, int ldW,
                                                    _Float16* __restrict__ WT, int Kr,
                                                    float scale) {
    __shared__ float t[64][65];
    int n0 = blockIdx.x * 64, k0 = blockIdx.y * 64;
    int tid = threadIdx.x;
    int r = tid >> 4, c4 = (tid & 15) * 4;
#pragma unroll
    for (int p = 0; p < 4; p++) {
        floatx4 v = *(const floatx4*)(W + (size_t)(k0 + r + p * 16) * ldW + n0 + c4);
#pragma unroll
        for (int j = 0; j < 4; j++) t[c4 + j][r + p * 16] = v[j];
    }
    __syncthreads();
#pragma unroll
    for (int p = 0; p < 4; p++) {
        int rr = r + p * 16;
        half4 o;
#pragma unroll
        for (int j = 0; j < 4; j++) o[j] = (_Float16)(t[rr][c4 + j] * scale);
        *(half4*)(WT + (size_t)(n0 + rr) * Kr + k0 + c4) = o;
    }
}

// ------- V transpose fp16: V[4096][ldv] (64-col head slices) -> Vt[bh=32][dh=64][s=2048] --
__global__ __launch_bounds__(256) void transv_kernel(const _Float16* __restrict__ V, int ldv,
                                                     _Float16* __restrict__ Vt) {
    __shared__ _Float16 t[64][72];
    int t0 = blockIdx.x * 64, d0 = blockIdx.y * 64;
    int tid = threadIdx.x;
#pragma unroll
    for (int i = 0; i < 2; i++) {
        int v = tid + i * 256;
        int r = v >> 3, c = (v & 7) * 8;
        half8 vv = *(const half8*)(V + (size_t)(t0 + r) * ldv + d0 + c);
#pragma unroll
        for (int j = 0; j < 8; j++) t[c + j][r] = vv[j];
    }
    __syncthreads();
    int bh = (t0 >> 11) * 16 + (d0 >> 6);
    int sbase = t0 & 2047;
#pragma unroll
    for (int i = 0; i < 2; i++) {
        int v = tid + i * 256;
        int r = v >> 3, c = (v & 7) * 8;
        half8 o = *(const half8*)&t[r][c];
        *(half8*)(Vt + ((size_t)bh * 64 + r) * 2048 + sbase + c) = o;
    }
}

// ------- MFMA GEMM 64x128 (round-5 proven): C = [relu](A@BT^T + bias) + res --------
// A [M][lda] fp16, BT [N][K] fp16. 4 waves x (32x64), BK=64.
__global__ __launch_bounds__(256) void gemm_t(const _Float16* __restrict__ A, int lda,
                                              const _Float16* __restrict__ BT,
                                              const float* __restrict__ bias,
                                              const float* res, void* Cout,
                                              int N, int K, int relu_flag, int out_fp16) {
    __shared__ _Float16 As[64 * 64];    // 8KB
    __shared__ _Float16 Bs[128 * 64];   // 16KB
    int tid = threadIdx.x;
    int wave = tid >> 6, lane = tid & 63, quad = lane >> 4, l15 = lane & 15;
    int bm = blockIdx.y * 64, bn = blockIdx.x * 128;
    int wr = (wave & 1) * 32, wc = (wave >> 1) * 64;
    int lrow = lane >> 3, lch = lane & 7;

    floatx4 acc[2][4];
#pragma unroll
    for (int im = 0; im < 2; im++)
#pragma unroll
        for (int in = 0; in < 4; in++)
#pragma unroll
            for (int r = 0; r < 4; r++) acc[im][in][r] = 0.f;

    for (int k0 = 0; k0 < K; k0 += 64) {
        __syncthreads();
#pragma unroll
        for (int ia = 0; ia < 2; ia++) {
            int g = 2 * wave + ia;
            int row = g * 8 + lrow;
            int ch = lch ^ (row & 7);
            async16(A + (size_t)(bm + row) * lda + k0 + ch * 8, &As[g * 512]);
        }
#pragma unroll
        for (int ib = 0; ib < 4; ib++) {
            int g = 4 * wave + ib;
            int row = g * 8 + lrow;
            int ch = lch ^ (row & 7);
            async16(BT + (size_t)(bn + row) * K + k0 + ch * 8, &Bs[g * 512]);
        }
        __syncthreads();

        half8 af[2][2], bf[4][2];
#pragma unroll
        for (int kk = 0; kk < 2; kk++) {
#pragma unroll
            for (int im = 0; im < 2; im++) {
                int m = wr + im * 16 + l15;
                af[im][kk] = *(const half8*)&As[m * 64 + ((((kk << 2) | quad) ^ (m & 7)) << 3)];
            }
#pragma unroll
            for (int in = 0; in < 4; in++) {
                int n = wc + in * 16 + l15;
                bf[in][kk] = *(const half8*)&Bs[n * 64 + ((((kk << 2) | quad) ^ (n & 7)) << 3)];
            }
        }
#pragma unroll
        for (int kk = 0; kk < 2; kk++)
#pragma unroll
            for (int im = 0; im < 2; im++)
#pragma unroll
                for (int in = 0; in < 4; in++)
                    acc[im][in] = __builtin_amdgcn_mfma_f32_16x16x32_f16(af[im][kk], bf[in][kk],
                                                                         acc[im][in], 0, 0, 0);
    }
#pragma unroll
    for (int im = 0; im < 2; im++)
#pragma unroll
        for (int in = 0; in < 4; in++)
#pragma unroll
            for (int r = 0; r < 4; r++) {
                int row = bm + wr + im * 16 + quad * 4 + r;
                int col = bn + wc + in * 16 + l15;
                float val = acc[im][in][r];
                if (bias) val += bias[col];
                if (relu_flag) val = fmaxf(val, 0.f);
                if (res) val += res[(size_t)row * N + col];
                if (out_fp16) ((_Float16*)Cout)[(size_t)row * N + col] = (_Float16)val;
                else          ((float*)Cout)[(size_t)row * N + col] = val;
            }
}

// ---------------- Flash attention v3: S^T trick + double-buffered K/V ----------
// Q pre-scaled by 1/sqrt(DH) (folded into wq). One barrier per kt iteration:
// prefetch kt+1 into buf[(kt+1)&1] right after the barrier, compute kt on buf[kt&1].
__global__ __launch_bounds__(256) void attn_kernel(const _Float16* Q,
                                                   const _Float16* __restrict__ K,
                                                   const _Float16* __restrict__ Vt,
                                                   _Float16* O, int ld) {
    __shared__ _Float16 Qs[64 * 64];          // 8KB
    __shared__ _Float16 KVs[2][2][64 * 64];   // [buf][0=K,1=V] 32KB
    int qt = blockIdx.x, bh = blockIdx.y;
    int b = bh >> 4, h = bh & 15;
    int col0 = h * 64, tbase = b * 2048;
    int tid = threadIdx.x;
    int wave = tid >> 6, lane = tid & 63, quad = lane >> 4, l15 = lane & 15;
    int lrow = lane >> 3, lch = lane & 7;

    // stage Q + first K/V
#pragma unroll
    for (int i = 0; i < 2; i++) {
        int g = 2 * wave + i;
        int row = g * 8 + lrow;
        int ch = lch ^ (row & 7);
        async16(Q + (size_t)(tbase + qt * 64 + row) * ld + col0 + ch * 8, &Qs[g * 512]);
        async16(K + (size_t)(tbase + row) * ld + col0 + ch * 8, &KVs[0][0][g * 512]);
        async16(Vt + ((size_t)bh * 64 + row) * 2048 + ch * 8, &KVs[0][1][g * 512]);
    }
    __syncthreads();   // drains Q + buf0

    // hoist Q fragments (Qs is read-only for the rest of the kernel)
    int rowq = 16 * wave + l15;
    half8 bq[2];
#pragma unroll
    for (int kk = 0; kk < 2; kk++)
        bq[kk] = *(const half8*)&Qs[rowq * 64 + ((((kk << 2) | quad) ^ (rowq & 7)) << 3)];

    floatx4 o_acc[4];
#pragma unroll
    for (int im = 0; im < 4; im++)
#pragma unroll
        for (int r = 0; r < 4; r++) o_acc[im][r] = 0.f;
    float m_i = -1e30f, l_i = 0.f;

    for (int kt = 0; kt < 32; kt++) {
        if (kt) __syncthreads();   // drains prefetch(kt); frees buf[(kt+1)&1] (read in kt-1)
        if (kt + 1 < 32) {
            int nb = (kt + 1) & 1;
#pragma unroll
            for (int i = 0; i < 2; i++) {
                int g = 2 * wave + i;
                int row = g * 8 + lrow;
                int ch = lch ^ (row & 7);
                async16(K + (size_t)(tbase + (kt + 1) * 64 + row) * ld + col0 + ch * 8,
                        &KVs[nb][0][g * 512]);
                async16(Vt + ((size_t)bh * 64 + row) * 2048 + (kt + 1) * 64 + ch * 8,
                        &KVs[nb][1][g * 512]);
            }
        }
        const _Float16* Ks = KVs[kt & 1][0];
        const _Float16* Vs = KVs[kt & 1][1];

        // S^T tiles: D[kidx = 16jn+quad*4+r][q = l15]
        floatx4 s_acc[4];
#pragma unroll
        for (int jn = 0; jn < 4; jn++)
#pragma unroll
            for (int r = 0; r < 4; r++) s_acc[jn][r] = 0.f;
#pragma unroll
        for (int jn = 0; jn < 4; jn++) {
            int rowk = 16 * jn + l15;
#pragma unroll
            for (int kk = 0; kk < 2; kk++) {
                half8 ak = *(const half8*)&Ks[rowk * 64 + ((((kk << 2) | quad) ^ (rowk & 7)) << 3)];
                s_acc[jn] = __builtin_amdgcn_mfma_f32_16x16x32_f16(ak, bq[kk], s_acc[jn], 0, 0, 0);
            }
        }

        // online softmax (scores pre-scaled via wq)
        float mx = -1e30f;
#pragma unroll
        for (int jn = 0; jn < 4; jn++)
#pragma unroll
            for (int r = 0; r < 4; r++) mx = fmaxf(mx, s_acc[jn][r]);
        mx = fmaxf(mx, __shfl_xor(mx, 16));
        mx = fmaxf(mx, __shfl_xor(mx, 32));
        float mnew = fmaxf(m_i, mx);
        float dd = m_i - mnew;
        float alpha = (dd < -60.f) ? 0.f : __expf(dd);
        m_i = mnew;

        float sum = 0.f;
#pragma unroll
        for (int jn = 0; jn < 4; jn++)
#pragma unroll
            for (int r = 0; r < 4; r++) {
                float d2 = s_acc[jn][r] - mnew;
                float p = (d2 < -60.f) ? 0.f : __expf(d2);
                s_acc[jn][r] = p;
                sum += p;
            }
        sum += __shfl_xor(sum, 16);
        sum += __shfl_xor(sum, 32);
        l_i = l_i * alpha + sum;

        // P^T C-layout regs ARE B-fragments of mfma_16x16x16 (k=quad*4+j)
        half4 pb[4];
#pragma unroll
        for (int jn = 0; jn < 4; jn++)
#pragma unroll
            for (int r = 0; r < 4; r++) pb[jn][r] = (_Float16)s_acc[jn][r];

#pragma unroll
        for (int im = 0; im < 4; im++)
#pragma unroll
            for (int r = 0; r < 4; r++) o_acc[im][r] *= alpha;
#pragma unroll
        for (int im = 0; im < 4; im++) {
            int rowv = 16 * im + l15;
#pragma unroll
            for (int ks = 0; ks < 4; ks++) {
                int off = rowv * 128 + ((((2 * ks) | (quad >> 1)) ^ (rowv & 7)) << 4) + (quad & 1) * 8;
                half4 av = *(const half4*)((const char*)Vs + off);
                o_acc[im] = __builtin_amdgcn_mfma_f32_16x16x16f16(av, pb[ks], o_acc[im], 0, 0, 0);
            }
        }
    }

    float rl = 1.f / l_i;
#pragma unroll
    for (int im = 0; im < 4; im++) {
        half4 o;
#pragma unroll
        for (int r = 0; r < 4; r++) o[r] = (_Float16)(o_acc[im][r] * rl);
        *(half4*)&O[(size_t)(tbase + qt * 64 + wave * 16 + l15) * ld + col0 + im * 16 + quad * 4] = o;
    }
}

extern "C" void kernel_launch(void* const* d_in, const int* in_sizes, int n_in,
                              void* d_out, int out_size, void* d_ws, size_t ws_size,
                              hipStream_t stream) {
    const float* x   = (const float*)d_in[0];
    const float* wq  = (const float*)d_in[1];
    const float* wk  = (const float*)d_in[2];
    const float* wv  = (const float*)d_in[3];
    const float* wo  = (const float*)d_in[4];
    const float* w1  = (const float*)d_in[5];
    const float* b1  = (const float*)d_in[6];
    const float* w2  = (const float*)d_in[7];
    const float* b2  = (const float*)d_in[8];
    const float* g1  = (const float*)d_in[9];
    const float* be1 = (const float*)d_in[10];
    const float* g2  = (const float*)d_in[11];
    const float* be2 = (const float*)d_in[12];

    const size_t M1 = (size_t)1 << 20;
    _Float16* R0  = (_Float16*)d_ws;       // h -> Vt -> woT -> h(LN2)
    _Float16* QKV = R0 + 4 * M1;           // [4096][3072]; later f(R1+R2) + scratch(R3)
    _Float16* R3  = R0 + 12 * M1;

    _Float16* wqkvT = (_Float16*)d_out;    // [3072][1024] fp16 scratch (dead after QKV GEMM)
    float* x1 = (float*)d_out;
    float* out = (float*)d_out;

    dim3 blk(256);

    // fused QKV weight transpose-convert; 1/sqrt(64) folded into wq
    convt_kernel<<<dim3(16, 16), blk, 0, stream>>>(wq, 1024, wqkvT, 1024, 0.125f);
    convt_kernel<<<dim3(16, 16), blk, 0, stream>>>(wk, 1024, wqkvT + (size_t)1024 * 1024, 1024, 1.f);
    convt_kernel<<<dim3(16, 16), blk, 0, stream>>>(wv, 1024, wqkvT + (size_t)2048 * 1024, 1024, 1.f);
    // h = LN1(x)
    ln_kernel<<<4096, blk, 0, stream>>>(x, g1, be1, R0);
    // fused QKV GEMM: [4096,3072] = h @ wqkvT^T
    gemm_t<<<dim3(24, 64), blk, 0, stream>>>(R0, 1024, wqkvT, nullptr, nullptr, QKV, 3072, 1024, 0, 1);
    // Vt (h dead) from V slice (cols 2048..3071)
    transv_kernel<<<dim3(64, 16), blk, 0, stream>>>(QKV + 2048, 3072, R0);
    // attention in-place over Q slice
    attn_kernel<<<dim3(32, 32), blk, 0, stream>>>(QKV, QKV + 1024, R0, QKV, 3072);
    // woT -> R0 (Vt dead), then x1 = attnout @ wo + x -> d_out
    convt_kernel<<<dim3(16, 16), blk, 0, stream>>>(wo, 1024, R0, 1024, 1.f);
    gemm_t<<<dim3(8, 64), blk, 0, stream>>>(QKV, 3072, R0, nullptr, x, x1, 1024, 1024, 0, 0);
    // h = LN2(x1) -> R0 (woT dead)
    ln_kernel<<<4096, blk, 0, stream>>>(x1, g2, be2, R0);
    // FFN in two 2048-wide halves; f = [4096,2048] fp16 over R1+R2 (QKV dead)
    _Float16* f = QKV;
    for (int hh = 0; hh < 2; hh++) {
        _Float16* w1Th = R3;
        _Float16* w2Th = R3 + 2 * M1;
        convt_kernel<<<dim3(32, 16), blk, 0, stream>>>(w1 + hh * 2048, 4096, w1Th, 1024, 1.f);
        gemm_t<<<dim3(16, 64), blk, 0, stream>>>(R0, 1024, w1Th, b1 + hh * 2048, nullptr, f,
                                                 2048, 1024, 1, 1);
        convt_kernel<<<dim3(16, 32), blk, 0, stream>>>(w2 + (size_t)hh * 2048 * 1024, 1024, w2Th, 2048, 1.f);
        gemm_t<<<dim3(8, 64), blk, 0, stream>>>(f, 2048, w2Th, (hh == 1) ? b2 : nullptr, x1, out,
                                                1024, 2048, 0, 0);
    }
}